// Round 6
// baseline (164.041 us; speedup 1.0000x reference)
//
#include <hip/hip_runtime.h>
#include <stdint.h>

// Problem constants (B,C,H,W = 8,256,48,48)
#define NB  8
#define NC  256
#define NCR 32
#define NSP 2304  // N = H*W
#define LOG2E 1.44269504088896340736f

typedef __attribute__((ext_vector_type(8))) short short8;   // 8 x bf16 (4 VGPRs)
typedef __attribute__((ext_vector_type(4))) float f32x4;    // MFMA C/D frag
typedef __attribute__((ext_vector_type(4))) unsigned short us4;
typedef __attribute__((ext_vector_type(2))) unsigned int u32x2;

__device__ __forceinline__ unsigned short f2bf(float f) {
  union { float f; unsigned u; } a; a.f = f;
  unsigned r = (a.u + 0x7FFFu + ((a.u >> 16) & 1u)) >> 16;  // RNE
  return (unsigned short)r;
}

__device__ __forceinline__ float fexp2(float x) {
#if __has_builtin(__builtin_amdgcn_exp2f)
  return __builtin_amdgcn_exp2f(x);
#else
  return __exp2f(x);
#endif
}

// pack 4 fp32 -> 4 bf16 (RNE) as two dwords
__device__ __forceinline__ u32x2 pack4bf(float a, float b, float c, float d) {
  u32x2 r;
#if __has_builtin(__builtin_amdgcn_cvt_pk_bf16_f32)
  typedef __attribute__((ext_vector_type(2))) __bf16 bf2;
  union { bf2 v; unsigned u; } lo, hi;
  lo.v = __builtin_amdgcn_cvt_pk_bf16_f32(a, b);
  hi.v = __builtin_amdgcn_cvt_pk_bf16_f32(c, d);
  r[0] = lo.u; r[1] = hi.u;
#else
  r[0] = (unsigned)f2bf(a) | ((unsigned)f2bf(b) << 16);
  r[1] = (unsigned)f2bf(c) | ((unsigned)f2bf(d) << 16);
#endif
  return r;
}

typedef __attribute__((address_space(1))) const void* gvoidp;
typedef __attribute__((address_space(3))) void* lvoidp;
#define GLOADLDS16(g, l) __builtin_amdgcn_global_load_lds((gvoidp)(g), (lvoidp)(l), 16, 0, 0)

// ---------------------------------------------------------------------------
// Kernel 0a: one-time weight prep. w1|w2|w3 -> bf16 WB[320][256] (same RNE).
__global__ __launch_bounds__(256) void k_wprep(const float* __restrict__ w1,
    const float* __restrict__ w2, const float* __restrict__ w3,
    unsigned short* __restrict__ WB) {
  const int idx = blockIdx.x * 256 + threadIdx.x;   // 0..20479
  const int gid = idx * 4;                          // element index
  const int row = gid >> 8, col = gid & 255;
  const float* src;
  if (row < 32)       src = w1 + (size_t)row * NC + col;
  else if (row < 64)  src = w2 + (size_t)(row - 32) * NC + col;
  else                src = w3 + (size_t)(row - 64) * NC + col;
  float4 v = *(const float4*)src;
  us4 pk;
  pk[0] = f2bf(v.x); pk[1] = f2bf(v.y); pk[2] = f2bf(v.z); pk[3] = f2bf(v.w);
  *(us4*)(WB + (size_t)row * NC + col) = pk;
}

// ---------------------------------------------------------------------------
// Kernel 0b: x[b][c][n] f32 -> XT[b][n][c] bf16 transpose (pure streaming).
// Per block: 32 n x 256 c tile. Register 4x4 transpose: 4x float4 loads
// (8 segments of 128B per inst) -> 4x 8B LDS writes (bank-optimal 4-way)
// -> 16B LDS reads -> 16B coalesced global stores. Same f2bf RNE as before.
__global__ __launch_bounds__(256) void k_xt(const float* __restrict__ x,
    unsigned short* __restrict__ XT) {
  __shared__ __align__(16) unsigned short xs[32][264];  // [n][c], +8 pad
  const int tile = blockIdx.x;          // 0..575
  const int b = tile / 72, n0 = (tile % 72) * 32;
  const int t = threadIdx.x, lane = t & 63, wave = t >> 6;
  const float* xb = x + (size_t)b * NC * NSP;
  const int cgl = lane & 7, n4g = lane >> 3;
#pragma unroll
  for (int p = 0; p < 2; ++p) {
    const int cg = (p * 4 + wave) * 8 + cgl;     // c-group 0..63 (4 rows each)
    const float* src = xb + (size_t)(cg * 4) * NSP + n0 + n4g * 4;
    f32x4 v0 = *(const f32x4*)(src);
    f32x4 v1 = *(const f32x4*)(src + NSP);
    f32x4 v2 = *(const f32x4*)(src + 2 * NSP);
    f32x4 v3 = *(const f32x4*)(src + 3 * NSP);
#pragma unroll
    for (int i = 0; i < 4; ++i) {
      us4 pk;
      pk[0] = f2bf(v0[i]); pk[1] = f2bf(v1[i]);
      pk[2] = f2bf(v2[i]); pk[3] = f2bf(v3[i]);
      *(us4*)&xs[n4g * 4 + i][cg * 4] = pk;      // 8B write
    }
  }
  __syncthreads();
  const int n = t >> 3;                          // 0..31
#pragma unroll
  for (int it = 0; it < 4; ++it) {
    const int chunk = (t & 7) + it * 8;          // 0..31 (16B c-chunks)
    short8 val = *(const short8*)&xs[n][chunk * 8];
    *(short8*)(XT + ((size_t)b * NSP + n0 + n) * NC + chunk * 8) = val;
  }
}

// ---------------------------------------------------------------------------
// Kernel 1 (QKV projection, pure GEMM): B-fragments load straight from XT
// (coalesced 16B global loads) — no staging, no transpose, no main-loop
// barrier. V epilogue goes through an LDS turnaround: scalar bf16 writes to
// Vt[256][40] (16B-aligned rows), one barrier, then cooperative 16B stores.
__global__ __launch_bounds__(256) void k_projg(const unsigned short* __restrict__ XT,
    const unsigned short* __restrict__ WB, const float* __restrict__ b1,
    const float* __restrict__ b2, const float* __restrict__ b3,
    unsigned short* __restrict__ Q, unsigned short* __restrict__ K,
    unsigned short* __restrict__ V) {
  __shared__ __align__(16) unsigned short Vt[256][40];  // 20480 B
  const int n0 = blockIdx.x * 32, b = blockIdx.y;
  const int t = threadIdx.x, lane = t & 63, wave = t >> 6;
  const int col = lane & 15, quad = lane >> 4;
  const unsigned short* xtb = XT + ((size_t)b * NSP + n0) * NC;
  const f32x4 zero4 = {0.f, 0.f, 0.f, 0.f};
  f32x4 acc[5][2];
#pragma unroll
  for (int i = 0; i < 5; ++i)
#pragma unroll
    for (int j = 0; j < 2; ++j) acc[i][j] = zero4;

  for (int kc = 0; kc < 8; ++kc) {
    short8 bfr[2];
#pragma unroll
    for (int nt = 0; nt < 2; ++nt)
      bfr[nt] = *(const short8*)(xtb + (size_t)(nt * 16 + col) * NC + kc * 32 + quad * 8);
#pragma unroll
    for (int ml = 0; ml < 5; ++ml) {
      const int m0 = (wave * 5 + ml) * 16;
      const short8 af = *(const short8*)(WB + (size_t)(m0 + col) * NC + kc * 32 + quad * 8);
#pragma unroll
      for (int nt = 0; nt < 2; ++nt)
        acc[ml][nt] = __builtin_amdgcn_mfma_f32_16x16x32_bf16(af, bfr[nt], acc[ml][nt], 0, 0, 0);
    }
  }
#pragma unroll
  for (int ml = 0; ml < 5; ++ml) {
    const int m0 = (wave * 5 + ml) * 16;
    const float* bias;
    if (m0 < 32)      bias = b1 + m0;
    else if (m0 < 64) bias = b2 + (m0 - 32);
    else              bias = b3 + (m0 - 64);
    float bv[4];
#pragma unroll
    for (int r = 0; r < 4; ++r) bv[r] = bias[quad * 4 + r];
    if (m0 < 64) {  // Q or K : [b][n][32] — packed 8B stores
      unsigned short* dst = (m0 < 32) ? Q : K;
      const float scl = (m0 < 32) ? LOG2E : 1.0f;  // fold log2e into Q
      const int d0 = (m0 & 31) + quad * 4;
#pragma unroll
      for (int nt = 0; nt < 2; ++nt) {
        const int n = n0 + nt * 16 + col;
        us4 pk;
#pragma unroll
        for (int r = 0; r < 4; ++r) pk[r] = f2bf((acc[ml][nt][r] + bv[r]) * scl);
        *(us4*)(dst + ((size_t)b * NSP + n) * NCR + d0) = pk;
      }
    } else {        // V : stage into LDS turnaround tile [c][n]
      const int cbase = m0 - 64 + quad * 4;
#pragma unroll
      for (int nt = 0; nt < 2; ++nt) {
#pragma unroll
        for (int r = 0; r < 4; ++r)
          Vt[cbase + r][nt * 16 + col] = f2bf(acc[ml][nt][r] + bv[r]);
      }
    }
  }
  __syncthreads();
  // cooperative V store: 256 c-rows x 32 n as 16B stores (16 segs x 64B/inst)
  const int chunk = t & 3;             // 16B chunk within the 32-n row
#pragma unroll
  for (int it = 0; it < 4; ++it) {
    const int c = (t >> 2) + it * 64;
    short8 val = *(const short8*)&Vt[c][chunk * 8];
    *(short8*)(V + ((size_t)b * NC + c) * NSP + n0 + chunk * 8) = val;
  }
}

// ---------------------------------------------------------------------------
// Kernel 1-fallback (R4 fused transpose+GEMM) — used only if ws_size cannot
// hold XT. Identical to R4's k_proj.
__global__ __launch_bounds__(256) void k_proj(const float* __restrict__ x,
    const unsigned short* __restrict__ WB, const float* __restrict__ b1,
    const float* __restrict__ b2, const float* __restrict__ b3,
    unsigned short* __restrict__ Q, unsigned short* __restrict__ K,
    unsigned short* __restrict__ V) {
  __shared__ unsigned short xs[32][264];  // [n][c], +8 pad
  const int n0 = blockIdx.x * 32, b = blockIdx.y;
  const int t = threadIdx.x, lane = t & 63, wave = t >> 6;
  const int col = lane & 15, quad = lane >> 4;
  const float* xb = x + (size_t)b * NC * NSP;
#pragma unroll
  for (int p = 0; p < 8; ++p) {
    const int crow = (t >> 3) + p * 32;     // 0..255
    const int n4 = (t & 7) * 4;             // 0..28
    float4 v = *(const float4*)(xb + (size_t)crow * NSP + n0 + n4);
    xs[n4 + 0][crow] = f2bf(v.x);
    xs[n4 + 1][crow] = f2bf(v.y);
    xs[n4 + 2][crow] = f2bf(v.z);
    xs[n4 + 3][crow] = f2bf(v.w);
  }
  __syncthreads();
  const f32x4 zero4 = {0.f, 0.f, 0.f, 0.f};
  f32x4 acc[5][2];
#pragma unroll
  for (int i = 0; i < 5; ++i)
#pragma unroll
    for (int j = 0; j < 2; ++j) acc[i][j] = zero4;

  for (int kc = 0; kc < 8; ++kc) {
    short8 bf[2];
#pragma unroll
    for (int nt = 0; nt < 2; ++nt)
      bf[nt] = *(const short8*)&xs[nt * 16 + col][kc * 32 + quad * 8];
#pragma unroll
    for (int ml = 0; ml < 5; ++ml) {
      const int m0 = (wave * 5 + ml) * 16;
      const short8 af = *(const short8*)(WB + (size_t)(m0 + col) * NC + kc * 32 + quad * 8);
#pragma unroll
      for (int nt = 0; nt < 2; ++nt)
        acc[ml][nt] = __builtin_amdgcn_mfma_f32_16x16x32_bf16(af, bf[nt], acc[ml][nt], 0, 0, 0);
    }
  }
#pragma unroll
  for (int ml = 0; ml < 5; ++ml) {
    const int m0 = (wave * 5 + ml) * 16;
    const float* bias;
    if (m0 < 32)      bias = b1 + m0;
    else if (m0 < 64) bias = b2 + (m0 - 32);
    else              bias = b3 + (m0 - 64);
    float bv[4];
#pragma unroll
    for (int r = 0; r < 4; ++r) bv[r] = bias[quad * 4 + r];
    if (m0 < 64) {
      unsigned short* dst = (m0 < 32) ? Q : K;
      const float scl = (m0 < 32) ? LOG2E : 1.0f;
      const int d0 = (m0 & 31) + quad * 4;
#pragma unroll
      for (int nt = 0; nt < 2; ++nt) {
        const int n = n0 + nt * 16 + col;
        us4 pk;
#pragma unroll
        for (int r = 0; r < 4; ++r) pk[r] = f2bf((acc[ml][nt][r] + bv[r]) * scl);
        *(us4*)(dst + ((size_t)b * NSP + n) * NCR + d0) = pk;
      }
    } else {
      const int cbase = m0 - 64 + quad * 4;
#pragma unroll
      for (int nt = 0; nt < 2; ++nt) {
        const int n = n0 + nt * 16 + col;
#pragma unroll
        for (int r = 0; r < 4; ++r)
          V[((size_t)b * NC + cbase + r) * NSP + n] = f2bf(acc[ml][nt][r] + bv[r]);
      }
    }
  }
}

// ---------------------------------------------------------------------------
// Kernel 2 (fused attention) — UNCHANGED from R4 (best measured: 64.8 µs).
__global__ __launch_bounds__(192) void k_attn(const unsigned short* __restrict__ Q,
    const unsigned short* __restrict__ K, const unsigned short* __restrict__ V,
    const float* __restrict__ feat, const float* __restrict__ gamma,
    float* __restrict__ out) {
  __shared__ __align__(16) unsigned short smem[19840];  // 39680 B
  unsigned short* Vs = smem;            // [buf][128 c][64 j] : 2 x 8192 u16
  unsigned short* Ps = smem + 16384;    // [wave][16 i][72] : 3 x 1152 u16
  // batch-per-XCD swizzle: lin&7 -> batch (one batch per XCD, L2-resident)
  const int lin = blockIdx.x;
  const int b = lin & 7;
  const int rest = lin >> 3;            // 0..95
  const int i0 = (rest % 48) * 48;
  const int ch = (rest / 48) * 128;
  const int t = threadIdx.x, lane = t & 63, wave = t >> 6;  // wave 0..2
  const int col = lane & 15, quad = lane >> 4;
  const int iw = i0 + wave * 16;
  const unsigned short* Qb = Q + (size_t)b * NSP * NCR;
  const unsigned short* Kb = K + (size_t)b * NSP * NCR;
  const unsigned short* Vb = V + (size_t)b * NC * NSP;
  unsigned short* PsW = Ps + wave * 1152;  // single buffer (wave-private)

  const short8 qa = *(const short8*)(Qb + (size_t)(iw + col) * NCR + quad * 8);
  const f32x4 zero4 = {0.f, 0.f, 0.f, 0.f};
  f32x4 acc[8];
#pragma unroll
  for (int ct = 0; ct < 8; ++ct) acc[ct] = zero4;
  float rs = 0.f;  // partial row-sum for i = col (this lane's quad's j-subset)
  // staging lane map: call q covers c-rows q*8..q*8+7 (8 rows x 8 chunks of 16B);
  // lane -> row r8 = lane>>3, phys chunk pc = lane&7 holding logical chunk pc^r8.
  const int r8 = lane >> 3, pc = lane & 7, jcs = pc ^ r8;

  // ---- prologue: kb(0), stage(0) -> buf0, scores(0) -> Ps
  short8 kb[4];
#pragma unroll
  for (int mt = 0; mt < 4; ++mt)
    kb[mt] = *(const short8*)(Kb + (size_t)(mt * 16 + col) * NCR + quad * 8);
#pragma unroll
  for (int cix = 0; cix < 6; ++cix) {
    const int q = wave * 6 + cix;          // 0..17; q>=16 skipped (wave-uniform)
    if (q < 16) {
      const unsigned short* g = Vb + (size_t)(ch + q * 8 + r8) * NSP + jcs * 8;
      GLOADLDS16(g, Vs + q * 512);
    }
  }
#pragma unroll
  for (int mt = 0; mt < 4; ++mt) {
    f32x4 s = __builtin_amdgcn_mfma_f32_16x16x32_bf16(kb[mt], qa, zero4, 0, 0, 0);
    const float e0 = fexp2(s[0]), e1 = fexp2(s[1]), e2 = fexp2(s[2]), e3 = fexp2(s[3]);
    rs += (e0 + e1) + (e2 + e3);
    *(u32x2*)(PsW + col * 72 + mt * 16 + quad * 4) = pack4bf(e0, e1, e2, e3);
  }

  // ---- main loop: one barrier per iteration
  for (int kc = 0; kc < 36; ++kc) {
    __syncthreads();  // Vs(kc) staged (vmcnt drained)
    const int bufc = kc & 1, bufn = bufc ^ 1;
    const int j1 = (kc + 1) * 64;
    const bool more = (kc + 1 < 36);
    if (more) {
      // kb(n+1) first (in-order vmcnt: retires before the staging loads)
#pragma unroll
      for (int mt = 0; mt < 4; ++mt)
        kb[mt] = *(const short8*)(Kb + (size_t)(j1 + mt * 16 + col) * NCR + quad * 8);
      // stage(n+1) -> Vs bufn (full PV+scores distance to drain before barrier)
#pragma unroll
      for (int cix = 0; cix < 6; ++cix) {
        const int q = wave * 6 + cix;
        if (q < 16) {
          const unsigned short* g = Vb + (size_t)(ch + q * 8 + r8) * NSP + j1 + jcs * 8;
          GLOADLDS16(g, Vs + bufn * 8192 + q * 512);
        }
      }
    }
    // PV(kc): reads Ps (this wave's, written last iter) + Vs bufc
    const unsigned short* vsc = Vs + bufc * 8192;
    __builtin_amdgcn_s_setprio(1);
#pragma unroll
    for (int kk = 0; kk < 2; ++kk) {
      const short8 pa = *(const short8*)(PsW + col * 72 + kk * 32 + quad * 8);
#pragma unroll
      for (int ct = 0; ct < 8; ++ct) {
        const short8 vbf = *(const short8*)(vsc + (ct * 16 + col) * 64 +
                                            (((kk * 4 + quad) ^ (col & 7)) * 8));
        acc[ct] = __builtin_amdgcn_mfma_f32_16x16x32_bf16(pa, vbf, acc[ct], 0, 0, 0);
      }
    }
    __builtin_amdgcn_s_setprio(0);
    if (more) {
      // scores(n+1) -> Ps (single buffer: overwrite AFTER this iter's PV reads;
      // wave-private + in-order DS makes this safe)
#pragma unroll
      for (int mt = 0; mt < 4; ++mt) {
        f32x4 s = __builtin_amdgcn_mfma_f32_16x16x32_bf16(kb[mt], qa, zero4, 0, 0, 0);
        const float e0 = fexp2(s[0]), e1 = fexp2(s[1]), e2 = fexp2(s[2]), e3 = fexp2(s[3]);
        rs += (e0 + e1) + (e2 + e3);
        *(u32x2*)(PsW + col * 72 + mt * 16 + quad * 4) = pack4bf(e0, e1, e2, e3);
      }
    }
  }

  // ---- l: sum the 4 quads of each col (full row-sum for i = col), then
  // redistribute to D-layout rows (i = quad*4 + r) for the epilogue.
  rs += __shfl_xor(rs, 16, 64);
  rs += __shfl_xor(rs, 32, 64);
  const float g = gamma[0];
  float rinv[4];
#pragma unroll
  for (int r = 0; r < 4; ++r) rinv[r] = g / __shfl(rs, quad * 4 + r, 64);

  // ---- epilogue: float4 over r (i-contiguous), 64B segments
  const float* fb = feat + (size_t)b * NC * NSP;
  float* ob = out + (size_t)b * NC * NSP;
#pragma unroll
  for (int ct = 0; ct < 8; ++ct) {
    const size_t a0 = (size_t)(ch + ct * 16 + col) * NSP + iw + quad * 4;
    float4 f = *(const float4*)(fb + a0);
    float4 o;
    o.x = acc[ct][0] * rinv[0] + f.x;
    o.y = acc[ct][1] * rinv[1] + f.y;
    o.z = acc[ct][2] * rinv[2] + f.z;
    o.w = acc[ct][3] * rinv[3] + f.w;
    *(float4*)(ob + a0) = o;
  }
}

// ---------------------------------------------------------------------------
// Workspace layout (bytes), total 21,397,504 (~20.4 MB):
//   Q  : [0, 1179648)            bf16 [8][2304][32]   (pre-scaled by log2e)
//   K  : [1179648, 2359296)      bf16 [8][2304][32]
//   V  : [2359296, 11796480)     bf16 [8][256][2304]
//   WB : [11796480, 11960320)    bf16 [320][256]      (w1|w2|w3 concat)
//   XT : [11960320, 21397504)    bf16 [8][2304][256]  (x transposed)
#define OFF_Q  0UL
#define OFF_K  1179648UL
#define OFF_V  2359296UL
#define OFF_WB 11796480UL
#define OFF_XT 11960320UL
#define WS_NEED (OFF_XT + 9437184UL)

extern "C" void kernel_launch(void* const* d_in, const int* in_sizes, int n_in,
                              void* d_out, int out_size, void* d_ws, size_t ws_size,
                              hipStream_t stream) {
  const float* feat  = (const float*)d_in[0];
  const float* w1    = (const float*)d_in[1];
  const float* b1    = (const float*)d_in[2];
  const float* w2    = (const float*)d_in[3];
  const float* b2    = (const float*)d_in[4];
  const float* w3    = (const float*)d_in[5];
  const float* b3    = (const float*)d_in[6];
  const float* gamma = (const float*)d_in[7];
  float* out = (float*)d_out;
  char* ws = (char*)d_ws;
  unsigned short* Q  = (unsigned short*)(ws + OFF_Q);
  unsigned short* K  = (unsigned short*)(ws + OFF_K);
  unsigned short* V  = (unsigned short*)(ws + OFF_V);
  unsigned short* WB = (unsigned short*)(ws + OFF_WB);
  unsigned short* XT = (unsigned short*)(ws + OFF_XT);

  hipLaunchKernelGGL(k_wprep, dim3(80), dim3(256), 0, stream, w1, w2, w3, WB);
  if (ws_size >= WS_NEED) {
    hipLaunchKernelGGL(k_xt, dim3(576), dim3(256), 0, stream, feat, XT);
    hipLaunchKernelGGL(k_projg, dim3(72, NB), dim3(256), 0, stream,
                       XT, WB, b1, b2, b3, Q, K, V);
  } else {
    hipLaunchKernelGGL(k_proj, dim3(72, NB), dim3(256), 0, stream,
                       feat, WB, b1, b2, b3, Q, K, V);
  }
  hipLaunchKernelGGL(k_attn, dim3(768), dim3(192), 0, stream,
                     Q, K, V, feat, gamma, out);
}

// Round 7
// 156.319 us; speedup vs baseline: 1.0494x; 1.0494x over previous
//
#include <hip/hip_runtime.h>
#include <stdint.h>

// Problem constants (B,C,H,W = 8,256,48,48)
#define NB  8
#define NC  256
#define NCR 32
#define NSP 2304  // N = H*W
#define LOG2E 1.44269504088896340736f

typedef __attribute__((ext_vector_type(8))) short short8;   // 8 x bf16 (4 VGPRs)
typedef __attribute__((ext_vector_type(4))) float f32x4;    // MFMA C/D frag
typedef __attribute__((ext_vector_type(4))) unsigned short us4;
typedef __attribute__((ext_vector_type(2))) unsigned int u32x2;

__device__ __forceinline__ unsigned short f2bf(float f) {
  union { float f; unsigned u; } a; a.f = f;
  unsigned r = (a.u + 0x7FFFu + ((a.u >> 16) & 1u)) >> 16;  // RNE
  return (unsigned short)r;
}

__device__ __forceinline__ float fexp2(float x) {
#if __has_builtin(__builtin_amdgcn_exp2f)
  return __builtin_amdgcn_exp2f(x);
#else
  return __exp2f(x);
#endif
}

// pack 4 fp32 -> 4 bf16 (RNE) as two dwords
__device__ __forceinline__ u32x2 pack4bf(float a, float b, float c, float d) {
  u32x2 r;
#if __has_builtin(__builtin_amdgcn_cvt_pk_bf16_f32)
  typedef __attribute__((ext_vector_type(2))) __bf16 bf2;
  union { bf2 v; unsigned u; } lo, hi;
  lo.v = __builtin_amdgcn_cvt_pk_bf16_f32(a, b);
  hi.v = __builtin_amdgcn_cvt_pk_bf16_f32(c, d);
  r[0] = lo.u; r[1] = hi.u;
#else
  r[0] = (unsigned)f2bf(a) | ((unsigned)f2bf(b) << 16);
  r[1] = (unsigned)f2bf(c) | ((unsigned)f2bf(d) << 16);
#endif
  return r;
}

typedef __attribute__((address_space(1))) const void* gvoidp;
typedef __attribute__((address_space(3))) void* lvoidp;
#define GLOADLDS16(g, l) __builtin_amdgcn_global_load_lds((gvoidp)(g), (lvoidp)(l), 16, 0, 0)

// ---------------------------------------------------------------------------
// Kernel 0: one-time weight prep. w1|w2|w3 -> bf16 WB[320][256] (same RNE).
__global__ __launch_bounds__(256) void k_wprep(const float* __restrict__ w1,
    const float* __restrict__ w2, const float* __restrict__ w3,
    unsigned short* __restrict__ WB) {
  const int idx = blockIdx.x * 256 + threadIdx.x;   // 0..20479
  const int gid = idx * 4;                          // element index
  const int row = gid >> 8, col = gid & 255;
  const float* src;
  if (row < 32)       src = w1 + (size_t)row * NC + col;
  else if (row < 64)  src = w2 + (size_t)(row - 32) * NC + col;
  else                src = w3 + (size_t)(row - 64) * NC + col;
  float4 v = *(const float4*)src;
  us4 pk;
  pk[0] = f2bf(v.x); pk[1] = f2bf(v.y); pk[2] = f2bf(v.z); pk[3] = f2bf(v.w);
  *(us4*)(WB + (size_t)row * NC + col) = pk;
}

// ---------------------------------------------------------------------------
// Kernel 1 (fused transpose + QKV projection), v2. R4 structure (proven best
// proj path) with its two slow internals replaced by R6-verified components:
//  - staging: register 4x4 transpose (from k_xt) -> 8x 8B DS writes/thread
//    instead of 32 scalar ds_write_b16;
//  - V epilogue: Vt[256][40] LDS turnaround (from k_projg) -> cooperative 16B
//    global stores instead of ~8K scalar 2B stores per block.
// Weights pre-converted (WB bf16); Q rows pre-scaled by log2(e).
__global__ __launch_bounds__(256) void k_proj(const float* __restrict__ x,
    const unsigned short* __restrict__ WB, const float* __restrict__ b1,
    const float* __restrict__ b2, const float* __restrict__ b3,
    unsigned short* __restrict__ Q, unsigned short* __restrict__ K,
    unsigned short* __restrict__ V) {
  __shared__ __align__(16) unsigned short xs[32][264];  // [n][c], +8 pad
  __shared__ __align__(16) unsigned short Vt[256][40];  // V turnaround, 20480 B
  const int n0 = blockIdx.x * 32, b = blockIdx.y;
  const int t = threadIdx.x, lane = t & 63, wave = t >> 6;
  const int col = lane & 15, quad = lane >> 4;
  const float* xb = x + (size_t)b * NC * NSP;
  // ---- staging: register 4x4 transpose, 8B LDS writes
  const int cgl = lane & 7, n4g = lane >> 3;
#pragma unroll
  for (int p = 0; p < 2; ++p) {
    const int cg = (p * 4 + wave) * 8 + cgl;     // c-group 0..63 (4 rows each)
    const float* src = xb + (size_t)(cg * 4) * NSP + n0 + n4g * 4;
    f32x4 v0 = *(const f32x4*)(src);
    f32x4 v1 = *(const f32x4*)(src + NSP);
    f32x4 v2 = *(const f32x4*)(src + 2 * NSP);
    f32x4 v3 = *(const f32x4*)(src + 3 * NSP);
#pragma unroll
    for (int i = 0; i < 4; ++i) {
      us4 pk;
      pk[0] = f2bf(v0[i]); pk[1] = f2bf(v1[i]);
      pk[2] = f2bf(v2[i]); pk[3] = f2bf(v3[i]);
      *(us4*)&xs[n4g * 4 + i][cg * 4] = pk;      // 8B write
    }
  }
  __syncthreads();
  const f32x4 zero4 = {0.f, 0.f, 0.f, 0.f};
  f32x4 acc[5][2];
#pragma unroll
  for (int i = 0; i < 5; ++i)
#pragma unroll
    for (int j = 0; j < 2; ++j) acc[i][j] = zero4;

  for (int kc = 0; kc < 8; ++kc) {
    short8 bf[2];
#pragma unroll
    for (int nt = 0; nt < 2; ++nt)
      bf[nt] = *(const short8*)&xs[nt * 16 + col][kc * 32 + quad * 8];
#pragma unroll
    for (int ml = 0; ml < 5; ++ml) {
      const int m0 = (wave * 5 + ml) * 16;
      const short8 af = *(const short8*)(WB + (size_t)(m0 + col) * NC + kc * 32 + quad * 8);
#pragma unroll
      for (int nt = 0; nt < 2; ++nt)
        acc[ml][nt] = __builtin_amdgcn_mfma_f32_16x16x32_bf16(af, bf[nt], acc[ml][nt], 0, 0, 0);
    }
  }
#pragma unroll
  for (int ml = 0; ml < 5; ++ml) {
    const int m0 = (wave * 5 + ml) * 16;
    const float* bias;
    if (m0 < 32)      bias = b1 + m0;
    else if (m0 < 64) bias = b2 + (m0 - 32);
    else              bias = b3 + (m0 - 64);
    float bv[4];
#pragma unroll
    for (int r = 0; r < 4; ++r) bv[r] = bias[quad * 4 + r];
    if (m0 < 64) {  // Q or K : [b][n][32] — packed 8B stores
      unsigned short* dst = (m0 < 32) ? Q : K;
      const float scl = (m0 < 32) ? LOG2E : 1.0f;  // fold log2e into Q
      const int d0 = (m0 & 31) + quad * 4;
#pragma unroll
      for (int nt = 0; nt < 2; ++nt) {
        const int n = n0 + nt * 16 + col;
        us4 pk;
#pragma unroll
        for (int r = 0; r < 4; ++r) pk[r] = f2bf((acc[ml][nt][r] + bv[r]) * scl);
        *(us4*)(dst + ((size_t)b * NSP + n) * NCR + d0) = pk;
      }
    } else {        // V : stage into LDS turnaround tile [c][n]
      const int cbase = m0 - 64 + quad * 4;
#pragma unroll
      for (int nt = 0; nt < 2; ++nt) {
#pragma unroll
        for (int r = 0; r < 4; ++r)
          Vt[cbase + r][nt * 16 + col] = f2bf(acc[ml][nt][r] + bv[r]);
      }
    }
  }
  __syncthreads();
  // cooperative V store: 256 c-rows x 32 n as 16B stores (16 segs x 64B/inst)
  const int chunk = t & 3;             // 16B chunk within the 32-n row
#pragma unroll
  for (int it = 0; it < 4; ++it) {
    const int c = (t >> 2) + it * 64;
    short8 val = *(const short8*)&Vt[c][chunk * 8];
    *(short8*)(V + ((size_t)b * NC + c) * NSP + n0 + chunk * 8) = val;
  }
}

// ---------------------------------------------------------------------------
// Kernel 2 (fused attention) — UNCHANGED from R4 (best measured: ~64.8 µs).
__global__ __launch_bounds__(192) void k_attn(const unsigned short* __restrict__ Q,
    const unsigned short* __restrict__ K, const unsigned short* __restrict__ V,
    const float* __restrict__ feat, const float* __restrict__ gamma,
    float* __restrict__ out) {
  __shared__ __align__(16) unsigned short smem[19840];  // 39680 B
  unsigned short* Vs = smem;            // [buf][128 c][64 j] : 2 x 8192 u16
  unsigned short* Ps = smem + 16384;    // [wave][16 i][72] : 3 x 1152 u16
  // batch-per-XCD swizzle: lin&7 -> batch (one batch per XCD, L2-resident)
  const int lin = blockIdx.x;
  const int b = lin & 7;
  const int rest = lin >> 3;            // 0..95
  const int i0 = (rest % 48) * 48;
  const int ch = (rest / 48) * 128;
  const int t = threadIdx.x, lane = t & 63, wave = t >> 6;  // wave 0..2
  const int col = lane & 15, quad = lane >> 4;
  const int iw = i0 + wave * 16;
  const unsigned short* Qb = Q + (size_t)b * NSP * NCR;
  const unsigned short* Kb = K + (size_t)b * NSP * NCR;
  const unsigned short* Vb = V + (size_t)b * NC * NSP;
  unsigned short* PsW = Ps + wave * 1152;  // single buffer (wave-private)

  const short8 qa = *(const short8*)(Qb + (size_t)(iw + col) * NCR + quad * 8);
  const f32x4 zero4 = {0.f, 0.f, 0.f, 0.f};
  f32x4 acc[8];
#pragma unroll
  for (int ct = 0; ct < 8; ++ct) acc[ct] = zero4;
  float rs = 0.f;  // partial row-sum for i = col (this lane's quad's j-subset)
  // staging lane map: call q covers c-rows q*8..q*8+7 (8 rows x 8 chunks of 16B);
  // lane -> row r8 = lane>>3, phys chunk pc = lane&7 holding logical chunk pc^r8.
  const int r8 = lane >> 3, pc = lane & 7, jcs = pc ^ r8;

  // ---- prologue: kb(0), stage(0) -> buf0, scores(0) -> Ps
  short8 kb[4];
#pragma unroll
  for (int mt = 0; mt < 4; ++mt)
    kb[mt] = *(const short8*)(Kb + (size_t)(mt * 16 + col) * NCR + quad * 8);
#pragma unroll
  for (int cix = 0; cix < 6; ++cix) {
    const int q = wave * 6 + cix;          // 0..17; q>=16 skipped (wave-uniform)
    if (q < 16) {
      const unsigned short* g = Vb + (size_t)(ch + q * 8 + r8) * NSP + jcs * 8;
      GLOADLDS16(g, Vs + q * 512);
    }
  }
#pragma unroll
  for (int mt = 0; mt < 4; ++mt) {
    f32x4 s = __builtin_amdgcn_mfma_f32_16x16x32_bf16(kb[mt], qa, zero4, 0, 0, 0);
    const float e0 = fexp2(s[0]), e1 = fexp2(s[1]), e2 = fexp2(s[2]), e3 = fexp2(s[3]);
    rs += (e0 + e1) + (e2 + e3);
    *(u32x2*)(PsW + col * 72 + mt * 16 + quad * 4) = pack4bf(e0, e1, e2, e3);
  }

  // ---- main loop: one barrier per iteration
  for (int kc = 0; kc < 36; ++kc) {
    __syncthreads();  // Vs(kc) staged (vmcnt drained)
    const int bufc = kc & 1, bufn = bufc ^ 1;
    const int j1 = (kc + 1) * 64;
    const bool more = (kc + 1 < 36);
    if (more) {
      // kb(n+1) first (in-order vmcnt: retires before the staging loads)
#pragma unroll
      for (int mt = 0; mt < 4; ++mt)
        kb[mt] = *(const short8*)(Kb + (size_t)(j1 + mt * 16 + col) * NCR + quad * 8);
      // stage(n+1) -> Vs bufn (full PV+scores distance to drain before barrier)
#pragma unroll
      for (int cix = 0; cix < 6; ++cix) {
        const int q = wave * 6 + cix;
        if (q < 16) {
          const unsigned short* g = Vb + (size_t)(ch + q * 8 + r8) * NSP + j1 + jcs * 8;
          GLOADLDS16(g, Vs + bufn * 8192 + q * 512);
        }
      }
    }
    // PV(kc): reads Ps (this wave's, written last iter) + Vs bufc
    const unsigned short* vsc = Vs + bufc * 8192;
    __builtin_amdgcn_s_setprio(1);
#pragma unroll
    for (int kk = 0; kk < 2; ++kk) {
      const short8 pa = *(const short8*)(PsW + col * 72 + kk * 32 + quad * 8);
#pragma unroll
      for (int ct = 0; ct < 8; ++ct) {
        const short8 vbf = *(const short8*)(vsc + (ct * 16 + col) * 64 +
                                            (((kk * 4 + quad) ^ (col & 7)) * 8));
        acc[ct] = __builtin_amdgcn_mfma_f32_16x16x32_bf16(pa, vbf, acc[ct], 0, 0, 0);
      }
    }
    __builtin_amdgcn_s_setprio(0);
    if (more) {
      // scores(n+1) -> Ps (single buffer: overwrite AFTER this iter's PV reads;
      // wave-private + in-order DS makes this safe)
#pragma unroll
      for (int mt = 0; mt < 4; ++mt) {
        f32x4 s = __builtin_amdgcn_mfma_f32_16x16x32_bf16(kb[mt], qa, zero4, 0, 0, 0);
        const float e0 = fexp2(s[0]), e1 = fexp2(s[1]), e2 = fexp2(s[2]), e3 = fexp2(s[3]);
        rs += (e0 + e1) + (e2 + e3);
        *(u32x2*)(PsW + col * 72 + mt * 16 + quad * 4) = pack4bf(e0, e1, e2, e3);
      }
    }
  }

  // ---- l: sum the 4 quads of each col (full row-sum for i = col), then
  // redistribute to D-layout rows (i = quad*4 + r) for the epilogue.
  rs += __shfl_xor(rs, 16, 64);
  rs += __shfl_xor(rs, 32, 64);
  const float g = gamma[0];
  float rinv[4];
#pragma unroll
  for (int r = 0; r < 4; ++r) rinv[r] = g / __shfl(rs, quad * 4 + r, 64);

  // ---- epilogue: float4 over r (i-contiguous), 64B segments
  const float* fb = feat + (size_t)b * NC * NSP;
  float* ob = out + (size_t)b * NC * NSP;
#pragma unroll
  for (int ct = 0; ct < 8; ++ct) {
    const size_t a0 = (size_t)(ch + ct * 16 + col) * NSP + iw + quad * 4;
    float4 f = *(const float4*)(fb + a0);
    float4 o;
    o.x = acc[ct][0] * rinv[0] + f.x;
    o.y = acc[ct][1] * rinv[1] + f.y;
    o.z = acc[ct][2] * rinv[2] + f.z;
    o.w = acc[ct][3] * rinv[3] + f.w;
    *(float4*)(ob + a0) = o;
  }
}

// ---------------------------------------------------------------------------
// Workspace layout (bytes), total 11,960,320 (~11.4 MB):
//   Q  : [0, 1179648)            bf16 [8][2304][32]   (pre-scaled by log2e)
//   K  : [1179648, 2359296)      bf16 [8][2304][32]
//   V  : [2359296, 11796480)     bf16 [8][256][2304]
//   WB : [11796480, 11960320)    bf16 [320][256]      (w1|w2|w3 concat)
#define OFF_Q  0UL
#define OFF_K  1179648UL
#define OFF_V  2359296UL
#define OFF_WB 11796480UL

extern "C" void kernel_launch(void* const* d_in, const int* in_sizes, int n_in,
                              void* d_out, int out_size, void* d_ws, size_t ws_size,
                              hipStream_t stream) {
  const float* feat  = (const float*)d_in[0];
  const float* w1    = (const float*)d_in[1];
  const float* b1    = (const float*)d_in[2];
  const float* w2    = (const float*)d_in[3];
  const float* b2    = (const float*)d_in[4];
  const float* w3    = (const float*)d_in[5];
  const float* b3    = (const float*)d_in[6];
  const float* gamma = (const float*)d_in[7];
  float* out = (float*)d_out;
  char* ws = (char*)d_ws;
  unsigned short* Q  = (unsigned short*)(ws + OFF_Q);
  unsigned short* K  = (unsigned short*)(ws + OFF_K);
  unsigned short* V  = (unsigned short*)(ws + OFF_V);
  unsigned short* WB = (unsigned short*)(ws + OFF_WB);

  hipLaunchKernelGGL(k_wprep, dim3(80), dim3(256), 0, stream, w1, w2, w3, WB);
  hipLaunchKernelGGL(k_proj, dim3(72, NB), dim3(256), 0, stream,
                     feat, WB, b1, b2, b3, Q, K, V);
  hipLaunchKernelGGL(k_attn, dim3(768), dim3(192), 0, stream,
                     Q, K, V, feat, gamma, out);
}

// Round 8
// 151.299 us; speedup vs baseline: 1.0842x; 1.0332x over previous
//
#include <hip/hip_runtime.h>
#include <stdint.h>

// Problem constants (B,C,H,W = 8,256,48,48)
#define NB  8
#define NC  256
#define NCR 32
#define NSP 2304  // N = H*W
#define LOG2E 1.44269504088896340736f

typedef __attribute__((ext_vector_type(8))) short short8;   // 8 x bf16 (4 VGPRs)
typedef __attribute__((ext_vector_type(4))) float f32x4;    // MFMA C/D frag
typedef __attribute__((ext_vector_type(4))) unsigned short us4;
typedef __attribute__((ext_vector_type(2))) unsigned int u32x2;

__device__ __forceinline__ unsigned short f2bf(float f) {
  union { float f; unsigned u; } a; a.f = f;
  unsigned r = (a.u + 0x7FFFu + ((a.u >> 16) & 1u)) >> 16;  // RNE
  return (unsigned short)r;
}

__device__ __forceinline__ float fexp2(float x) {
#if __has_builtin(__builtin_amdgcn_exp2f)
  return __builtin_amdgcn_exp2f(x);
#else
  return __exp2f(x);
#endif
}

// pack 4 fp32 -> 4 bf16 (RNE) as two dwords
__device__ __forceinline__ u32x2 pack4bf(float a, float b, float c, float d) {
  u32x2 r;
#if __has_builtin(__builtin_amdgcn_cvt_pk_bf16_f32)
  typedef __attribute__((ext_vector_type(2))) __bf16 bf2;
  union { bf2 v; unsigned u; } lo, hi;
  lo.v = __builtin_amdgcn_cvt_pk_bf16_f32(a, b);
  hi.v = __builtin_amdgcn_cvt_pk_bf16_f32(c, d);
  r[0] = lo.u; r[1] = hi.u;
#else
  r[0] = (unsigned)f2bf(a) | ((unsigned)f2bf(b) << 16);
  r[1] = (unsigned)f2bf(c) | ((unsigned)f2bf(d) << 16);
#endif
  return r;
}

typedef __attribute__((address_space(1))) const void* gvoidp;
typedef __attribute__((address_space(3))) void* lvoidp;
#define GLOADLDS16(g, l) __builtin_amdgcn_global_load_lds((gvoidp)(g), (lvoidp)(l), 16, 0, 0)

// ---------------------------------------------------------------------------
// Kernel 0: one-time weight prep. w1|w2|w3 -> bf16 WB[320][256] (same RNE).
__global__ __launch_bounds__(256) void k_wprep(const float* __restrict__ w1,
    const float* __restrict__ w2, const float* __restrict__ w3,
    unsigned short* __restrict__ WB) {
  const int idx = blockIdx.x * 256 + threadIdx.x;   // 0..20479
  const int gid = idx * 4;                          // element index
  const int row = gid >> 8, col = gid & 255;
  const float* src;
  if (row < 32)       src = w1 + (size_t)row * NC + col;
  else if (row < 64)  src = w2 + (size_t)(row - 32) * NC + col;
  else                src = w3 + (size_t)(row - 64) * NC + col;
  float4 v = *(const float4*)src;
  us4 pk;
  pk[0] = f2bf(v.x); pk[1] = f2bf(v.y); pk[2] = f2bf(v.z); pk[3] = f2bf(v.w);
  *(us4*)(WB + (size_t)row * NC + col) = pk;
}

// ---------------------------------------------------------------------------
// Kernel 1 (fused transpose + QKV projection) — UNCHANGED from R7 (~4 µs,
// near its traffic roofline).
__global__ __launch_bounds__(256) void k_proj(const float* __restrict__ x,
    const unsigned short* __restrict__ WB, const float* __restrict__ b1,
    const float* __restrict__ b2, const float* __restrict__ b3,
    unsigned short* __restrict__ Q, unsigned short* __restrict__ K,
    unsigned short* __restrict__ V) {
  __shared__ __align__(16) unsigned short xs[32][264];  // [n][c], +8 pad
  __shared__ __align__(16) unsigned short Vt[256][40];  // V turnaround, 20480 B
  const int n0 = blockIdx.x * 32, b = blockIdx.y;
  const int t = threadIdx.x, lane = t & 63, wave = t >> 6;
  const int col = lane & 15, quad = lane >> 4;
  const float* xb = x + (size_t)b * NC * NSP;
  // ---- staging: register 4x4 transpose, 8B LDS writes
  const int cgl = lane & 7, n4g = lane >> 3;
#pragma unroll
  for (int p = 0; p < 2; ++p) {
    const int cg = (p * 4 + wave) * 8 + cgl;     // c-group 0..63 (4 rows each)
    const float* src = xb + (size_t)(cg * 4) * NSP + n0 + n4g * 4;
    f32x4 v0 = *(const f32x4*)(src);
    f32x4 v1 = *(const f32x4*)(src + NSP);
    f32x4 v2 = *(const f32x4*)(src + 2 * NSP);
    f32x4 v3 = *(const f32x4*)(src + 3 * NSP);
#pragma unroll
    for (int i = 0; i < 4; ++i) {
      us4 pk;
      pk[0] = f2bf(v0[i]); pk[1] = f2bf(v1[i]);
      pk[2] = f2bf(v2[i]); pk[3] = f2bf(v3[i]);
      *(us4*)&xs[n4g * 4 + i][cg * 4] = pk;      // 8B write
    }
  }
  __syncthreads();
  const f32x4 zero4 = {0.f, 0.f, 0.f, 0.f};
  f32x4 acc[5][2];
#pragma unroll
  for (int i = 0; i < 5; ++i)
#pragma unroll
    for (int j = 0; j < 2; ++j) acc[i][j] = zero4;

  for (int kc = 0; kc < 8; ++kc) {
    short8 bf[2];
#pragma unroll
    for (int nt = 0; nt < 2; ++nt)
      bf[nt] = *(const short8*)&xs[nt * 16 + col][kc * 32 + quad * 8];
#pragma unroll
    for (int ml = 0; ml < 5; ++ml) {
      const int m0 = (wave * 5 + ml) * 16;
      const short8 af = *(const short8*)(WB + (size_t)(m0 + col) * NC + kc * 32 + quad * 8);
#pragma unroll
      for (int nt = 0; nt < 2; ++nt)
        acc[ml][nt] = __builtin_amdgcn_mfma_f32_16x16x32_bf16(af, bf[nt], acc[ml][nt], 0, 0, 0);
    }
  }
#pragma unroll
  for (int ml = 0; ml < 5; ++ml) {
    const int m0 = (wave * 5 + ml) * 16;
    const float* bias;
    if (m0 < 32)      bias = b1 + m0;
    else if (m0 < 64) bias = b2 + (m0 - 32);
    else              bias = b3 + (m0 - 64);
    float bv[4];
#pragma unroll
    for (int r = 0; r < 4; ++r) bv[r] = bias[quad * 4 + r];
    if (m0 < 64) {  // Q or K : [b][n][32] — packed 8B stores
      unsigned short* dst = (m0 < 32) ? Q : K;
      const float scl = (m0 < 32) ? LOG2E : 1.0f;  // fold log2e into Q
      const int d0 = (m0 & 31) + quad * 4;
#pragma unroll
      for (int nt = 0; nt < 2; ++nt) {
        const int n = n0 + nt * 16 + col;
        us4 pk;
#pragma unroll
        for (int r = 0; r < 4; ++r) pk[r] = f2bf((acc[ml][nt][r] + bv[r]) * scl);
        *(us4*)(dst + ((size_t)b * NSP + n) * NCR + d0) = pk;
      }
    } else {        // V : stage into LDS turnaround tile [c][n]
      const int cbase = m0 - 64 + quad * 4;
#pragma unroll
      for (int nt = 0; nt < 2; ++nt) {
#pragma unroll
        for (int r = 0; r < 4; ++r)
          Vt[cbase + r][nt * 16 + col] = f2bf(acc[ml][nt][r] + bv[r]);
      }
    }
  }
  __syncthreads();
  // cooperative V store: 256 c-rows x 32 n as 16B stores (16 segs x 64B/inst)
  const int chunk = t & 3;             // 16B chunk within the 32-n row
#pragma unroll
  for (int it = 0; it < 4; ++it) {
    const int c = (t >> 2) + it * 64;
    short8 val = *(const short8*)&Vt[c][chunk * 8];
    *(short8*)(V + ((size_t)b * NC + c) * NSP + n0 + chunk * 8) = val;
  }
}

// ---------------------------------------------------------------------------
// Kernel 2 (fused attention) — R7 structure with two micro-changes:
//  (a) row-sum via ones-MFMA: acc1 = mfma(pa, ones, acc1) (2 MFMA/iter)
//      replaces 16 scalar rs-adds/iter + end shuffles. D-layout (row =
//      quad*4+r) delivers rowsums directly in the epilogue register layout.
//  (b) s_setprio(1) also wraps the scores MFMA cluster (was PV-only).
__global__ __launch_bounds__(192) void k_attn(const unsigned short* __restrict__ Q,
    const unsigned short* __restrict__ K, const unsigned short* __restrict__ V,
    const float* __restrict__ feat, const float* __restrict__ gamma,
    float* __restrict__ out) {
  __shared__ __align__(16) unsigned short smem[19840];  // 39680 B
  unsigned short* Vs = smem;            // [buf][128 c][64 j] : 2 x 8192 u16
  unsigned short* Ps = smem + 16384;    // [wave][16 i][72] : 3 x 1152 u16
  // batch-per-XCD swizzle: lin&7 -> batch (one batch per XCD, L2-resident)
  const int lin = blockIdx.x;
  const int b = lin & 7;
  const int rest = lin >> 3;            // 0..95
  const int i0 = (rest % 48) * 48;
  const int ch = (rest / 48) * 128;
  const int t = threadIdx.x, lane = t & 63, wave = t >> 6;  // wave 0..2
  const int col = lane & 15, quad = lane >> 4;
  const int iw = i0 + wave * 16;
  const unsigned short* Qb = Q + (size_t)b * NSP * NCR;
  const unsigned short* Kb = K + (size_t)b * NSP * NCR;
  const unsigned short* Vb = V + (size_t)b * NC * NSP;
  unsigned short* PsW = Ps + wave * 1152;  // single buffer (wave-private)

  const short8 qa = *(const short8*)(Qb + (size_t)(iw + col) * NCR + quad * 8);
  const f32x4 zero4 = {0.f, 0.f, 0.f, 0.f};
  const short8 onesf = {0x3F80, 0x3F80, 0x3F80, 0x3F80,
                        0x3F80, 0x3F80, 0x3F80, 0x3F80};  // 8 x bf16(1.0)
  f32x4 acc[8];
#pragma unroll
  for (int ct = 0; ct < 8; ++ct) acc[ct] = zero4;
  f32x4 acc1 = zero4;  // rowsum accumulator: acc1[r] = sum_j P[i=quad*4+r][j]
  // staging lane map: call q covers c-rows q*8..q*8+7 (8 rows x 8 chunks of 16B);
  // lane -> row r8 = lane>>3, phys chunk pc = lane&7 holding logical chunk pc^r8.
  const int r8 = lane >> 3, pc = lane & 7, jcs = pc ^ r8;

  // ---- prologue: kb(0), stage(0) -> buf0, scores(0) -> Ps
  short8 kb[4];
#pragma unroll
  for (int mt = 0; mt < 4; ++mt)
    kb[mt] = *(const short8*)(Kb + (size_t)(mt * 16 + col) * NCR + quad * 8);
#pragma unroll
  for (int cix = 0; cix < 6; ++cix) {
    const int q = wave * 6 + cix;          // 0..17; q>=16 skipped (wave-uniform)
    if (q < 16) {
      const unsigned short* g = Vb + (size_t)(ch + q * 8 + r8) * NSP + jcs * 8;
      GLOADLDS16(g, Vs + q * 512);
    }
  }
#pragma unroll
  for (int mt = 0; mt < 4; ++mt) {
    f32x4 s = __builtin_amdgcn_mfma_f32_16x16x32_bf16(kb[mt], qa, zero4, 0, 0, 0);
    const float e0 = fexp2(s[0]), e1 = fexp2(s[1]), e2 = fexp2(s[2]), e3 = fexp2(s[3]);
    *(u32x2*)(PsW + col * 72 + mt * 16 + quad * 4) = pack4bf(e0, e1, e2, e3);
  }

  // ---- main loop: one barrier per iteration
  for (int kc = 0; kc < 36; ++kc) {
    __syncthreads();  // Vs(kc) staged (vmcnt drained)
    const int bufc = kc & 1, bufn = bufc ^ 1;
    const int j1 = (kc + 1) * 64;
    const bool more = (kc + 1 < 36);
    if (more) {
      // kb(n+1) first (in-order vmcnt: retires before the staging loads)
#pragma unroll
      for (int mt = 0; mt < 4; ++mt)
        kb[mt] = *(const short8*)(Kb + (size_t)(j1 + mt * 16 + col) * NCR + quad * 8);
      // stage(n+1) -> Vs bufn (full PV+scores distance to drain before barrier)
#pragma unroll
      for (int cix = 0; cix < 6; ++cix) {
        const int q = wave * 6 + cix;
        if (q < 16) {
          const unsigned short* g = Vb + (size_t)(ch + q * 8 + r8) * NSP + j1 + jcs * 8;
          GLOADLDS16(g, Vs + bufn * 8192 + q * 512);
        }
      }
    }
    // PV(kc): reads Ps (this wave's, written last iter) + Vs bufc
    const unsigned short* vsc = Vs + bufc * 8192;
    __builtin_amdgcn_s_setprio(1);
#pragma unroll
    for (int kk = 0; kk < 2; ++kk) {
      const short8 pa = *(const short8*)(PsW + col * 72 + kk * 32 + quad * 8);
#pragma unroll
      for (int ct = 0; ct < 8; ++ct) {
        const short8 vbf = *(const short8*)(vsc + (ct * 16 + col) * 64 +
                                            (((kk * 4 + quad) ^ (col & 7)) * 8));
        acc[ct] = __builtin_amdgcn_mfma_f32_16x16x32_bf16(pa, vbf, acc[ct], 0, 0, 0);
      }
      acc1 = __builtin_amdgcn_mfma_f32_16x16x32_bf16(pa, onesf, acc1, 0, 0, 0);
    }
    __builtin_amdgcn_s_setprio(0);
    if (more) {
      // scores(n+1) -> Ps (single buffer: overwrite AFTER this iter's PV reads;
      // wave-private + in-order DS makes this safe)
      __builtin_amdgcn_s_setprio(1);
#pragma unroll
      for (int mt = 0; mt < 4; ++mt) {
        f32x4 s = __builtin_amdgcn_mfma_f32_16x16x32_bf16(kb[mt], qa, zero4, 0, 0, 0);
        const float e0 = fexp2(s[0]), e1 = fexp2(s[1]), e2 = fexp2(s[2]), e3 = fexp2(s[3]);
        *(u32x2*)(PsW + col * 72 + mt * 16 + quad * 4) = pack4bf(e0, e1, e2, e3);
      }
      __builtin_amdgcn_s_setprio(0);
    }
  }

  // ---- epilogue: rowsums arrive in-register via acc1 (D row = quad*4 + r),
  // no shuffles needed. float4 over r (i-contiguous), 64B segments.
  const float g = gamma[0];
  float rinv[4];
#pragma unroll
  for (int r = 0; r < 4; ++r) rinv[r] = g / acc1[r];

  const float* fb = feat + (size_t)b * NC * NSP;
  float* ob = out + (size_t)b * NC * NSP;
#pragma unroll
  for (int ct = 0; ct < 8; ++ct) {
    const size_t a0 = (size_t)(ch + ct * 16 + col) * NSP + iw + quad * 4;
    float4 f = *(const float4*)(fb + a0);
    float4 o;
    o.x = acc[ct][0] * rinv[0] + f.x;
    o.y = acc[ct][1] * rinv[1] + f.y;
    o.z = acc[ct][2] * rinv[2] + f.z;
    o.w = acc[ct][3] * rinv[3] + f.w;
    *(float4*)(ob + a0) = o;
  }
}

// ---------------------------------------------------------------------------
// Workspace layout (bytes), total 11,960,320 (~11.4 MB):
//   Q  : [0, 1179648)            bf16 [8][2304][32]   (pre-scaled by log2e)
//   K  : [1179648, 2359296)      bf16 [8][2304][32]
//   V  : [2359296, 11796480)     bf16 [8][256][2304]
//   WB : [11796480, 11960320)    bf16 [320][256]      (w1|w2|w3 concat)
#define OFF_Q  0UL
#define OFF_K  1179648UL
#define OFF_V  2359296UL
#define OFF_WB 11796480UL

extern "C" void kernel_launch(void* const* d_in, const int* in_sizes, int n_in,
                              void* d_out, int out_size, void* d_ws, size_t ws_size,
                              hipStream_t stream) {
  const float* feat  = (const float*)d_in[0];
  const float* w1    = (const float*)d_in[1];
  const float* b1    = (const float*)d_in[2];
  const float* w2    = (const float*)d_in[3];
  const float* b2    = (const float*)d_in[4];
  const float* w3    = (const float*)d_in[5];
  const float* b3    = (const float*)d_in[6];
  const float* gamma = (const float*)d_in[7];
  float* out = (float*)d_out;
  char* ws = (char*)d_ws;
  unsigned short* Q  = (unsigned short*)(ws + OFF_Q);
  unsigned short* K  = (unsigned short*)(ws + OFF_K);
  unsigned short* V  = (unsigned short*)(ws + OFF_V);
  unsigned short* WB = (unsigned short*)(ws + OFF_WB);

  hipLaunchKernelGGL(k_wprep, dim3(80), dim3(256), 0, stream, w1, w2, w3, WB);
  hipLaunchKernelGGL(k_proj, dim3(72, NB), dim3(256), 0, stream,
                     feat, WB, b1, b2, b3, Q, K, V);
  hipLaunchKernelGGL(k_attn, dim3(768), dim3(192), 0, stream,
                     Q, K, V, feat, gamma, out);
}